// Round 8
// baseline (700.070 us; speedup 1.0000x reference)
//
#include <hip/hip_runtime.h>
#include <cmath>

// ---------------------------------------------------------------------------
// EquivariantCorrectionHead — round 8: latency attack on the R7 structure.
// - h0: 4 independent accumulators (dep chain 92 -> 23); g: 2 accumulators.
// - Software-pipelined global loads (prefetch next group's t2s row + scalars
//   into regs during compute; consumed at next iteration top).
// - __launch_bounds__(512,4): pin VGPR <= 128 (16 waves/CU; above 128 the
//   8-wave block quantization drops to 1 block/CU).
// - tb rows padded to 8 floats (b128 reads in phase 2); phase-9 reduction
//   packed into 3 words (15 ds_bpermute vs 25).
// Everything else identical to the verified R7 kernel.
// ---------------------------------------------------------------------------

#define DEVINL static __device__ __forceinline__

typedef _Float16 half2_t __attribute__((ext_vector_type(2)));
typedef _Float16 half8_t __attribute__((ext_vector_type(8)));
union H8 { half8_t v; half2_t p[4]; };

// ---- slab offsets in HALVES (all rows 16B-aligned; stride = 8*odd) ----
#define HW000 0        // 32 x 136 (stride 136 = 8*17): sym-tri(16) pairs, c0 folded
#define HW110 4352     // 32 x 56  (45 used, pads 0):   sym-tri(9), c0/sqrt5
#define HWC   6144     // 32 x 152 (144 used): [v][u],  c2/sqrt5*(w011+w101^T)
#define HW111 11008    // 32 x 56  (45 used, pads 0):   sym-tri(9), c2
#define HV110 12800    // 32 x 40  (32 used)
#define HMR   14080    // 32 x 40  (32 used): d/sqrt5*(v010^T+v100)
#define SLABH 15360

__device__ __align__(16) _Float16 g_wsh[SLABH];

struct CPack { float v[32]; };

// C222 nonzero superset (exact O(3) parity selection rule)
static constexpr int CIa[32] = {2,2,2,4,2,4,4,4, 2,0,0, 2,1,1, 2,3,3, 4,0,0, 4,1,1, 4,3,3, 0,0,1,1,3,3};
static constexpr int CJa[32] = {2,2,4,2,4,2,4,4, 0,2,0, 1,2,1, 3,2,3, 0,4,0, 1,4,1, 3,4,3, 1,3,0,3,0,1};
static constexpr int CKa[32] = {2,4,2,2,4,4,2,4, 0,0,2, 1,1,2, 3,3,2, 0,0,4, 1,1,4, 3,3,4, 3,1,3,0,1,0};

__host__ __device__ inline void tri_uv(int p, int n, int& u, int& v) {
  int base = 0;
  for (int x = 0; x < n; x++) {
    int c = n - x;
    if (p < base + c) { u = x; v = x + (p - base); return; }
    base += c;
  }
  u = n - 1; v = n - 1;
}

// ---- host analytic C222 (round-4 proven sign) ----
static double h_trE3(const double A[3][3], const double B[3][3], const double C[3][3]) {
  double t = 0.0;
  for (int r = 0; r < 3; r++)
    for (int c = 0; c < 3; c++) {
      double ab = 0.0;
      for (int m = 0; m < 3; m++) ab += A[r][m] * B[m][c];
      t += ab * C[c][r];
    }
  return t;
}
static void computeC(CPack& out) {
  const double s2i = 0.7071067811865475244, s6i = 0.4082482904638630164;
  double E[5][3][3] = {
    {{0, s2i, 0}, {s2i, 0, 0}, {0, 0, 0}},
    {{0, 0, 0}, {0, 0, s2i}, {0, s2i, 0}},
    {{-s6i, 0, 0}, {0, -s6i, 0}, {0, 0, 2.0 * s6i}},
    {{0, 0, s2i}, {0, 0, 0}, {s2i, 0, 0}},
    {{s2i, 0, 0}, {0, -s2i, 0}, {0, 0, 0}}
  };
  double T[125], nrm = 0.0;
  for (int f = 0; f < 125; f++) {
    int i = f / 25, j = (f / 5) % 5, k = f % 5;
    T[f] = h_trE3(E[i], E[j], E[k]) + h_trE3(E[i], E[k], E[j]);
    nrm += T[f] * T[f];
  }
  nrm = std::sqrt(nrm);
  int am = 0; double mx = std::fabs(T[0]);
  for (int q = 1; q < 125; q++) { double v = std::fabs(T[q]); if (v > mx) { mx = v; am = q; } }
  const double scale = ((T[am] < 0.0) ? 1.0 : -1.0) / nrm;   // round-4 sign
  for (int s = 0; s < 32; s++)
    out.v[s] = (float)(scale * T[(CIa[s] * 5 + CJa[s]) * 5 + CKa[s]]);
}

// ---- device helpers ----
DEVINL float dot2f(half2_t a, half2_t b, float c) {
#if __has_builtin(__builtin_amdgcn_fdot2)
  return __builtin_amdgcn_fdot2(a, b, c, false);
#else
  return fmaf((float)a[0], (float)b[0], fmaf((float)a[1], (float)b[1], c));
#endif
}
DEVINL half2_t pk2(float a, float b) {
  auto r = __builtin_amdgcn_cvt_pkrtz(a, b);
  half2_t o;
  __builtin_memcpy(&o, &r, sizeof(o));
  return o;
}
DEVINL int h2i(half2_t h) { int i; __builtin_memcpy(&i, &h, 4); return i; }
DEVINL half2_t i2h(int i) { half2_t h; __builtin_memcpy(&h, &i, 4); return h; }

// ---------------------------------------------------------------------------
// Setup: pack fp16 weight slab (symmetrized, constants folded)
// ---------------------------------------------------------------------------
__global__ void ech_setup(const float* __restrict__ w000, const float* __restrict__ w110,
                          const float* __restrict__ w011, const float* __restrict__ w101,
                          const float* __restrict__ w111, const float* __restrict__ v010,
                          const float* __restrict__ v100, const float* __restrict__ v110) {
  const float c0   = 1.0f / sqrtf(337.0f);
  const float inv5 = 0.44721359549995794f;
  const float c2   = sqrtf(5.0f / 369.0f);
  const float dm   = sqrtf(5.0f / 3072.0f) * inv5;
  int gid = blockIdx.x * blockDim.x + threadIdx.x;
  int gs  = gridDim.x * blockDim.x;

  for (int idx = gid; idx < 32 * 136; idx += gs) {        // w000
    int w = idx / 136, p = idx % 136; int u, v; tri_uv(p, 16, u, v);
    float x = c0 * (w000[(u * 16 + v) * 32 + w] + (u != v ? w000[(v * 16 + u) * 32 + w] : 0.0f));
    g_wsh[HW000 + w * 136 + p] = (_Float16)x;
  }
  for (int idx = gid; idx < 32 * 56; idx += gs) {         // w110 (+zero pads)
    int w = idx / 56, p = idx % 56; float x = 0.0f;
    if (p < 45) { int u, v; tri_uv(p, 9, u, v);
      x = c0 * inv5 * (w110[(u * 9 + v) * 32 + w] + (u != v ? w110[(v * 9 + u) * 32 + w] : 0.0f)); }
    g_wsh[HW110 + w * 56 + p] = (_Float16)x;
  }
  for (int idx = gid; idx < 32 * 144; idx += gs) {        // wc: [v][u]
    int w = idx / 144, r = idx % 144, v = r / 16, u = r % 16;
    float x = c2 * inv5 * (w011[(u * 9 + v) * 32 + w] + w101[(v * 16 + u) * 32 + w]);
    g_wsh[HWC + w * 152 + v * 16 + u] = (_Float16)x;
  }
  for (int idx = gid; idx < 32 * 56; idx += gs) {         // w111 (+zero pads)
    int w = idx / 56, p = idx % 56; float x = 0.0f;
    if (p < 45) { int u, v; tri_uv(p, 9, u, v);
      x = c2 * (w111[(u * 9 + v) * 32 + w] + (u != v ? w111[(v * 9 + u) * 32 + w] : 0.0f)); }
    g_wsh[HW111 + w * 56 + p] = (_Float16)x;
  }
  for (int idx = gid; idx < 1024; idx += gs) {            // v110 rows
    int u = idx / 32, v = idx % 32;
    g_wsh[HV110 + u * 40 + v] = (_Float16)v110[u * 32 + v];
  }
  for (int idx = gid; idx < 1024; idx += gs) {            // Mr
    int w = idx / 32, u = idx % 32;
    g_wsh[HMR + w * 40 + u] = (_Float16)(dm * (v010[u * 32 + w] + v100[w * 32 + u]));
  }
}

// ---------------------------------------------------------------------------
// Main fused kernel
// ---------------------------------------------------------------------------
#define ESZ 436
__global__ void __launch_bounds__(512, 4)
ech_main(const float* __restrict__ sc, const float* __restrict__ t2s,
         float* __restrict__ out, int nGroups, CPack C) {
  __shared__ __align__(16) _Float16 slabh[SLABH];
  __shared__ __align__(16) float scr[16 * ESZ];
  __shared__ int pairs9[48];
  __shared__ int sspair[68];

  const int tid  = threadIdx.x;
  const int lane = tid & 31;
  const int sub  = tid >> 5;
  const int w    = lane;

  for (int i = tid; i < SLABH / 8; i += 512)
    ((float4*)slabh)[i] = ((const float4*)g_wsh)[i];
  if (tid < 45) { int u, v; tri_uv(tid, 9, u, v); pairs9[tid] = u | (v << 4); }
  if (tid < 68) {
    int u0, v0, u1, v1;
    tri_uv(2 * tid, 16, u0, v0);
    tri_uv(2 * tid + 1, 16, u1, v1);
    sspair[tid] = u0 | (v0 << 4) | (u1 << 8) | (v1 << 12);
  }
  __syncthreads();

  constexpr int L2R[8] = {0, 1, 2, 4, 24, 26, 35, 38};

  // per-element scratch layout (words; all 16B-aligned)
  float*     E    = scr + sub * ESZ;
  float*     Araw = E;                          // 200 words (overlaid by qhh/h2hh)
  _Float16*  qhh  = (_Float16*)E;               // [5][48] halves  (words 0..119)
  _Float16*  h2hh = (_Float16*)(E + 120);       // [5][32] halves  (words 120..199)
  float*     tb   = E + 200;                    // [9][8] f32 padded rows (200..271)
  _Float16*  sshh = (_Float16*)(E + 272);       // 136 halves (272..339)
  _Float16*  tthh = (_Float16*)(E + 340);       // 48 halves (340..363)
  _Float16*  thh  = (_Float16*)(E + 364);       // [5][16] halves (364..403)
  _Float16*  h0hh = (_Float16*)(E + 404);       // 32 halves (404..419)
  float*     sL   = E + 420;                    // 16 f32 (420..435)

  // ---- software pipeline: prefetch group data into registers ----
  float4 p0, p1, psl;
  auto prefetch = [&](int g) {
    int bb = g * 16 + sub;
    const float4* s4 = (const float4*)(t2s + (size_t)bb * 200);
    p0 = s4[lane];
    if (lane < 18) p1 = s4[lane + 32];
    if (lane < 4)  psl = ((const float4*)(sc + (size_t)bb * 16))[lane];
  };
  prefetch(blockIdx.x);

  for (int grp = blockIdx.x; grp < nGroups; grp += gridDim.x) {
    const int b = grp * 16 + sub;

    // ---- phase 0: commit prefetched raw t2s + scalars to LDS; re-prefetch ----
    {
      float4* Av = (float4*)Araw;
      Av[lane] = p0;
      if (lane < 18) Av[lane + 32] = p1;
      if (lane < 4)  ((float4*)sL)[lane] = psl;
    }
    {
      int ng = grp + gridDim.x;
      prefetch(ng < nGroups ? ng : grp);
    }
    float sreg[16];
    {
      const float4* sv = (const float4*)(sc + (size_t)b * 16);
      #pragma unroll
      for (int i4 = 0; i4 < 4; i4++) {
        float4 x = sv[i4];
        sreg[4 * i4 + 0] = x.x; sreg[4 * i4 + 1] = x.y;
        sreg[4 * i4 + 2] = x.z; sreg[4 * i4 + 3] = x.w;
      }
    }

    // ---- phase 1: build t rows (fp32 tb padded + fp16 th transposed) ----
    #pragma unroll
    for (int it = 0; it < 2; it++) {
      int idx = lane + 32 * it;
      if (idx < 40) {
        int r = idx / 5, c = idx % 5;
        float val = Araw[L2R[r] * 5 + c];
        tb[r * 8 + c] = val;
        thh[c * 16 + r] = (_Float16)val;
      }
    }
    { // kernel-sum row: 25 lanes partial + width-32 shfl gather
      int l25 = lane % 25;
      int c2 = l25 / 5, j2 = l25 % 5;
      float acc = 0.f;
      #pragma unroll
      for (int rr = 0; rr < 8; rr++) acc += Araw[(j2 + 5 * rr) * 5 + c2];
      float tot = __shfl(acc, 5 * c2 + 0, 32) + __shfl(acc, 5 * c2 + 1, 32)
                + __shfl(acc, 5 * c2 + 2, 32) + __shfl(acc, 5 * c2 + 3, 32)
                + __shfl(acc, 5 * c2 + 4, 32);
      if (lane < 25 && j2 == 0) { tb[64 + c2] = tot; thh[c2 * 16 + 8] = (_Float16)tot; }
    }
    // ---- zero all fp16 pads (regions overlay poisoned/raw data) ----
    if (lane < 23) {
      if (lane < 15)      qhh[(lane / 3) * 48 + 45 + lane % 3] = (_Float16)0.f;
      else if (lane < 18) tthh[45 + (lane - 15)] = (_Float16)0.f;
      else                thh[(lane - 18) * 16 + 9] = (_Float16)0.f;
    }

    // ---- phase 2: pairs -> tt (fp16) + qT (fp16) ----
    #pragma unroll
    for (int it = 0; it < 2; it++) {
      int idx = lane + 32 * it;
      if (idx < 45) {
        int pr = pairs9[idx];
        int pu = pr & 15, pv = pr >> 4;
        float4 u4 = *(const float4*)(tb + pu * 8); float u5 = tb[pu * 8 + 4];
        float4 v4 = *(const float4*)(tb + pv * 8); float v5 = tb[pv * 8 + 4];
        float tu[5] = {u4.x, u4.y, u4.z, u4.w, u5};
        float tv[5] = {v4.x, v4.y, v4.z, v4.w, v5};
        float tt = tu[0]*tv[0] + tu[1]*tv[1] + tu[2]*tv[2] + tu[3]*tv[3] + tu[4]*tv[4];
        tthh[idx] = (_Float16)tt;
        float qk[5] = {0, 0, 0, 0, 0};
        #pragma unroll
        for (int s = 0; s < 32; s++)
          qk[CKa[s]] = fmaf(C.v[s], tu[CIa[s]] * tv[CJa[s]], qk[CKa[s]]);
        #pragma unroll
        for (int k = 0; k < 5; k++) qhh[k * 48 + idx] = (_Float16)qk[k];
      }
    }

    // ---- phase 3a: ss pair products (fp16) ----
    #pragma unroll
    for (int ii = 0; ii < 3; ii++) {
      int slot = lane + 32 * ii;
      if (slot < 68) {
        int t = sspair[slot];
        int u0 = t & 15, v0 = (t >> 4) & 15, u1 = (t >> 8) & 15, v1 = (t >> 12) & 15;
        *(half2_t*)(sshh + 2 * slot) = pk2(sL[u0] * sL[v0], sL[u1] * sL[v1]);
      }
    }

    // ---- phase 3b: h0[w] = W000.ss + W110.tt (4 independent acc chains) ----
    float h0;
    {
      float hA = 0.f, hB = 0.f, hC = 0.f, hD = 0.f;
      const _Float16* wr = slabh + HW000 + w * 136;
      #pragma unroll
      for (int i = 0; i < 17; i++) {
        H8 a, d;
        a.v = *(const half8_t*)(wr + 8 * i);
        d.v = *(const half8_t*)(sshh + 8 * i);
        hA = dot2f(a.p[0], d.p[0], hA); hB = dot2f(a.p[1], d.p[1], hB);
        hC = dot2f(a.p[2], d.p[2], hC); hD = dot2f(a.p[3], d.p[3], hD);
      }
      const _Float16* wr2 = slabh + HW110 + w * 56;
      #pragma unroll
      for (int i = 0; i < 6; i++) {
        H8 a, d;
        a.v = *(const half8_t*)(wr2 + 8 * i);
        d.v = *(const half8_t*)(tthh + 8 * i);
        hA = dot2f(a.p[0], d.p[0], hA); hB = dot2f(a.p[1], d.p[1], hB);
        hC = dot2f(a.p[2], d.p[2], hC); hD = dot2f(a.p[3], d.p[3], hD);
      }
      h0 = (hA + hB) + (hC + hD);
    }
    h0hh[w] = (_Float16)h0;

    // ---- phase 4: Cvv = WC.s ; h2 = Cvv.t ----
    half2_t sh[8];
    #pragma unroll
    for (int i = 0; i < 8; i++) sh[i] = pk2(sreg[2 * i], sreg[2 * i + 1]);
    float Cvv[9];
    {
      const _Float16* wr = slabh + HWC + w * 152;
      #pragma unroll
      for (int v = 0; v < 9; v++) {
        H8 a0, a1;
        a0.v = *(const half8_t*)(wr + v * 16);
        a1.v = *(const half8_t*)(wr + v * 16 + 8);
        float acc = dot2f(a0.p[0], sh[0], 0.f);
        acc = dot2f(a0.p[1], sh[1], acc); acc = dot2f(a0.p[2], sh[2], acc);
        acc = dot2f(a0.p[3], sh[3], acc); acc = dot2f(a1.p[0], sh[4], acc);
        acc = dot2f(a1.p[1], sh[5], acc); acc = dot2f(a1.p[2], sh[6], acc);
        acc = dot2f(a1.p[3], sh[7], acc);
        Cvv[v] = acc;
      }
    }
    half2_t cpk[5] = { pk2(Cvv[0], Cvv[1]), pk2(Cvv[2], Cvv[3]),
                       pk2(Cvv[4], Cvv[5]), pk2(Cvv[6], Cvv[7]), pk2(Cvv[8], 0.f) };
    float h2r[5];
    #pragma unroll
    for (int k = 0; k < 5; k++) {
      H8 d; d.v = *(const half8_t*)(thh + k * 16);
      half2_t d4 = *(const half2_t*)(thh + k * 16 + 8);
      float acc = dot2f(cpk[0], d.p[0], 0.f);
      acc = dot2f(cpk[1], d.p[1], acc);
      acc = dot2f(cpk[2], d.p[2], acc);
      acc = dot2f(cpk[3], d.p[3], acc);
      acc = dot2f(cpk[4], d4, acc);
      h2r[k] = acc;
    }

    // ---- phase 5: h2 += W111 . qT ----
    {
      H8 wk[6];
      const _Float16* wr = slabh + HW111 + w * 56;
      #pragma unroll
      for (int i = 0; i < 6; i++) wk[i].v = *(const half8_t*)(wr + 8 * i);
      #pragma unroll
      for (int k = 0; k < 5; k++) {
        const _Float16* qr = qhh + k * 48;
        float acc = h2r[k];
        #pragma unroll
        for (int i = 0; i < 6; i++) {
          H8 d; d.v = *(const half8_t*)(qr + 8 * i);
          acc = dot2f(wk[i].p[0], d.p[0], acc); acc = dot2f(wk[i].p[1], d.p[1], acc);
          acc = dot2f(wk[i].p[2], d.p[2], acc); acc = dot2f(wk[i].p[3], d.p[3], acc);
        }
        h2r[k] = acc;
      }
    }

    // ---- phase 6: h2 -> fp16 rows [j][32] ----
    #pragma unroll
    for (int k = 0; k < 5; k++) h2hh[k * 32 + w] = (_Float16)h2r[k];

    // ---- phase 7: a[j] = V110[w,:] . h2[:,j] ----
    float a5[5];
    {
      H8 wk[4];
      const _Float16* wr = slabh + HV110 + w * 40;
      #pragma unroll
      for (int i = 0; i < 4; i++) wk[i].v = *(const half8_t*)(wr + 8 * i);
      #pragma unroll
      for (int j = 0; j < 5; j++) {
        const _Float16* hr = h2hh + j * 32;
        float acc = 0.f;
        #pragma unroll
        for (int i = 0; i < 4; i++) {
          H8 d; d.v = *(const half8_t*)(hr + 8 * i);
          acc = dot2f(wk[i].p[0], d.p[0], acc); acc = dot2f(wk[i].p[1], d.p[1], acc);
          acc = dot2f(wk[i].p[2], d.p[2], acc); acc = dot2f(wk[i].p[3], d.p[3], acc);
        }
        a5[j] = acc;
      }
    }

    // ---- phase 8: g = Mr[w,:] . h0 (2 acc chains) ----
    float g;
    {
      float gA = 0.f, gB = 0.f;
      const _Float16* wr = slabh + HMR + w * 40;
      #pragma unroll
      for (int i = 0; i < 4; i++) {
        H8 a, d;
        a.v = *(const half8_t*)(wr + 8 * i);
        d.v = *(const half8_t*)(h0hh + 8 * i);
        gA = dot2f(a.p[0], d.p[0], gA); gB = dot2f(a.p[1], d.p[1], gB);
        gA = dot2f(a.p[2], d.p[2], gA); gB = dot2f(a.p[3], d.p[3], gB);
      }
      g = gA + gB;
    }

    // ---- phase 9: yv = C.(h2 (x) a); z = DCONST*yv + g*h2; packed reduce ----
    float yv[5] = {0, 0, 0, 0, 0};
    #pragma unroll
    for (int s = 0; s < 32; s++)
      yv[CKa[s]] = fmaf(C.v[s], h2r[CIa[s]] * a5[CJa[s]], yv[CKa[s]]);

    const float DCONST = sqrtf(5.0f / 3072.0f);
    float z[5];
    #pragma unroll
    for (int k = 0; k < 5; k++) z[k] = fmaf(DCONST, yv[k], g * h2r[k]);

    half2_t z01 = pk2(z[0], z[1]);
    half2_t z23 = pk2(z[2], z[3]);
    float   z4  = z[4];
    #pragma unroll
    for (int st = 1; st <= 16; st <<= 1) {
      z01 = z01 + i2h(__shfl_xor(h2i(z01), st));
      z23 = z23 + i2h(__shfl_xor(h2i(z23), st));
      z4 += __shfl_xor(z4, st);
    }
    if (lane < 5) {
      float val = (lane == 0) ? (float)z01[0]
                : (lane == 1) ? (float)z01[1]
                : (lane == 2) ? (float)z23[0]
                : (lane == 3) ? (float)z23[1] : z4;
      out[(size_t)b * 5 + lane] = val;
    }
  }
}

// ---------------------------------------------------------------------------
extern "C" void kernel_launch(void* const* d_in, const int* in_sizes, int n_in,
                              void* d_out, int out_size, void* d_ws, size_t ws_size,
                              hipStream_t stream) {
  (void)n_in; (void)out_size; (void)d_ws; (void)ws_size;

  CPack C;
  computeC(C);

  ech_setup<<<64, 256, 0, stream>>>(
      (const float*)d_in[2], (const float*)d_in[3], (const float*)d_in[4],
      (const float*)d_in[5], (const float*)d_in[6], (const float*)d_in[7],
      (const float*)d_in[8], (const float*)d_in[9]);

  const int B = in_sizes[0] / 16;
  const int nGroups = B / 16;
  ech_main<<<512, 512, 0, stream>>>(
      (const float*)d_in[0], (const float*)d_in[1], (float*)d_out, nGroups, C);
}

// Round 9
// 407.508 us; speedup vs baseline: 1.7179x; 1.7179x over previous
//
#include <hip/hip_runtime.h>
#include <cmath>

// ---------------------------------------------------------------------------
// EquivariantCorrectionHead — round 9: R7 structure + safe latency wins only.
// (R8 post-mortem: register prefetch + __launch_bounds__(512,4) caused VGPR
//  spill to scratch — FETCH 62MB->1.5GB. Both reverted.)
// Kept from R8: 4-acc h0 chain, 2-acc g chain, tb 8-word padded rows (b128
// reads in phase 2), packed 3-word final reduction.
// ---------------------------------------------------------------------------

#define DEVINL static __device__ __forceinline__

typedef _Float16 half2_t __attribute__((ext_vector_type(2)));
typedef _Float16 half8_t __attribute__((ext_vector_type(8)));
union H8 { half8_t v; half2_t p[4]; };

// ---- slab offsets in HALVES (all rows 16B-aligned; stride = 8*odd) ----
#define HW000 0        // 32 x 136 (stride 136 = 8*17): sym-tri(16) pairs, c0 folded
#define HW110 4352     // 32 x 56  (45 used, pads 0):   sym-tri(9), c0/sqrt5
#define HWC   6144     // 32 x 152 (144 used): [v][u],  c2/sqrt5*(w011+w101^T)
#define HW111 11008    // 32 x 56  (45 used, pads 0):   sym-tri(9), c2
#define HV110 12800    // 32 x 40  (32 used)
#define HMR   14080    // 32 x 40  (32 used): d/sqrt5*(v010^T+v100)
#define SLABH 15360

__device__ __align__(16) _Float16 g_wsh[SLABH];

struct CPack { float v[32]; };

// C222 nonzero superset (exact O(3) parity selection rule)
static constexpr int CIa[32] = {2,2,2,4,2,4,4,4, 2,0,0, 2,1,1, 2,3,3, 4,0,0, 4,1,1, 4,3,3, 0,0,1,1,3,3};
static constexpr int CJa[32] = {2,2,4,2,4,2,4,4, 0,2,0, 1,2,1, 3,2,3, 0,4,0, 1,4,1, 3,4,3, 1,3,0,3,0,1};
static constexpr int CKa[32] = {2,4,2,2,4,4,2,4, 0,0,2, 1,1,2, 3,3,2, 0,0,4, 1,1,4, 3,3,4, 3,1,3,0,1,0};

__host__ __device__ inline void tri_uv(int p, int n, int& u, int& v) {
  int base = 0;
  for (int x = 0; x < n; x++) {
    int c = n - x;
    if (p < base + c) { u = x; v = x + (p - base); return; }
    base += c;
  }
  u = n - 1; v = n - 1;
}

// ---- host analytic C222 (round-4 proven sign) ----
static double h_trE3(const double A[3][3], const double B[3][3], const double C[3][3]) {
  double t = 0.0;
  for (int r = 0; r < 3; r++)
    for (int c = 0; c < 3; c++) {
      double ab = 0.0;
      for (int m = 0; m < 3; m++) ab += A[r][m] * B[m][c];
      t += ab * C[c][r];
    }
  return t;
}
static void computeC(CPack& out) {
  const double s2i = 0.7071067811865475244, s6i = 0.4082482904638630164;
  double E[5][3][3] = {
    {{0, s2i, 0}, {s2i, 0, 0}, {0, 0, 0}},
    {{0, 0, 0}, {0, 0, s2i}, {0, s2i, 0}},
    {{-s6i, 0, 0}, {0, -s6i, 0}, {0, 0, 2.0 * s6i}},
    {{0, 0, s2i}, {0, 0, 0}, {s2i, 0, 0}},
    {{s2i, 0, 0}, {0, -s2i, 0}, {0, 0, 0}}
  };
  double T[125], nrm = 0.0;
  for (int f = 0; f < 125; f++) {
    int i = f / 25, j = (f / 5) % 5, k = f % 5;
    T[f] = h_trE3(E[i], E[j], E[k]) + h_trE3(E[i], E[k], E[j]);
    nrm += T[f] * T[f];
  }
  nrm = std::sqrt(nrm);
  int am = 0; double mx = std::fabs(T[0]);
  for (int q = 1; q < 125; q++) { double v = std::fabs(T[q]); if (v > mx) { mx = v; am = q; } }
  const double scale = ((T[am] < 0.0) ? 1.0 : -1.0) / nrm;   // round-4 sign
  for (int s = 0; s < 32; s++)
    out.v[s] = (float)(scale * T[(CIa[s] * 5 + CJa[s]) * 5 + CKa[s]]);
}

// ---- device helpers ----
DEVINL float dot2f(half2_t a, half2_t b, float c) {
#if __has_builtin(__builtin_amdgcn_fdot2)
  return __builtin_amdgcn_fdot2(a, b, c, false);
#else
  return fmaf((float)a[0], (float)b[0], fmaf((float)a[1], (float)b[1], c));
#endif
}
DEVINL half2_t pk2(float a, float b) {
  auto r = __builtin_amdgcn_cvt_pkrtz(a, b);
  half2_t o;
  __builtin_memcpy(&o, &r, sizeof(o));
  return o;
}
DEVINL int h2i(half2_t h) { int i; __builtin_memcpy(&i, &h, 4); return i; }
DEVINL half2_t i2h(int i) { half2_t h; __builtin_memcpy(&h, &i, 4); return h; }

// ---------------------------------------------------------------------------
// Setup: pack fp16 weight slab (symmetrized, constants folded)
// ---------------------------------------------------------------------------
__global__ void ech_setup(const float* __restrict__ w000, const float* __restrict__ w110,
                          const float* __restrict__ w011, const float* __restrict__ w101,
                          const float* __restrict__ w111, const float* __restrict__ v010,
                          const float* __restrict__ v100, const float* __restrict__ v110) {
  const float c0   = 1.0f / sqrtf(337.0f);
  const float inv5 = 0.44721359549995794f;
  const float c2   = sqrtf(5.0f / 369.0f);
  const float dm   = sqrtf(5.0f / 3072.0f) * inv5;
  int gid = blockIdx.x * blockDim.x + threadIdx.x;
  int gs  = gridDim.x * blockDim.x;

  for (int idx = gid; idx < 32 * 136; idx += gs) {        // w000
    int w = idx / 136, p = idx % 136; int u, v; tri_uv(p, 16, u, v);
    float x = c0 * (w000[(u * 16 + v) * 32 + w] + (u != v ? w000[(v * 16 + u) * 32 + w] : 0.0f));
    g_wsh[HW000 + w * 136 + p] = (_Float16)x;
  }
  for (int idx = gid; idx < 32 * 56; idx += gs) {         // w110 (+zero pads)
    int w = idx / 56, p = idx % 56; float x = 0.0f;
    if (p < 45) { int u, v; tri_uv(p, 9, u, v);
      x = c0 * inv5 * (w110[(u * 9 + v) * 32 + w] + (u != v ? w110[(v * 9 + u) * 32 + w] : 0.0f)); }
    g_wsh[HW110 + w * 56 + p] = (_Float16)x;
  }
  for (int idx = gid; idx < 32 * 144; idx += gs) {        // wc: [v][u]
    int w = idx / 144, r = idx % 144, v = r / 16, u = r % 16;
    float x = c2 * inv5 * (w011[(u * 9 + v) * 32 + w] + w101[(v * 16 + u) * 32 + w]);
    g_wsh[HWC + w * 152 + v * 16 + u] = (_Float16)x;
  }
  for (int idx = gid; idx < 32 * 56; idx += gs) {         // w111 (+zero pads)
    int w = idx / 56, p = idx % 56; float x = 0.0f;
    if (p < 45) { int u, v; tri_uv(p, 9, u, v);
      x = c2 * (w111[(u * 9 + v) * 32 + w] + (u != v ? w111[(v * 9 + u) * 32 + w] : 0.0f)); }
    g_wsh[HW111 + w * 56 + p] = (_Float16)x;
  }
  for (int idx = gid; idx < 1024; idx += gs) {            // v110 rows
    int u = idx / 32, v = idx % 32;
    g_wsh[HV110 + u * 40 + v] = (_Float16)v110[u * 32 + v];
  }
  for (int idx = gid; idx < 1024; idx += gs) {            // Mr
    int w = idx / 32, u = idx % 32;
    g_wsh[HMR + w * 40 + u] = (_Float16)(dm * (v010[u * 32 + w] + v100[w * 32 + u]));
  }
}

// ---------------------------------------------------------------------------
// Main fused kernel
// ---------------------------------------------------------------------------
#define ESZ 436
__global__ void __launch_bounds__(512)
ech_main(const float* __restrict__ sc, const float* __restrict__ t2s,
         float* __restrict__ out, int nGroups, CPack C) {
  __shared__ __align__(16) _Float16 slabh[SLABH];
  __shared__ __align__(16) float scr[16 * ESZ];
  __shared__ int pairs9[48];
  __shared__ int sspair[68];

  const int tid  = threadIdx.x;
  const int lane = tid & 31;
  const int sub  = tid >> 5;
  const int w    = lane;

  for (int i = tid; i < SLABH / 8; i += 512)
    ((float4*)slabh)[i] = ((const float4*)g_wsh)[i];
  if (tid < 45) { int u, v; tri_uv(tid, 9, u, v); pairs9[tid] = u | (v << 4); }
  if (tid < 68) {
    int u0, v0, u1, v1;
    tri_uv(2 * tid, 16, u0, v0);
    tri_uv(2 * tid + 1, 16, u1, v1);
    sspair[tid] = u0 | (v0 << 4) | (u1 << 8) | (v1 << 12);
  }
  __syncthreads();

  constexpr int L2R[8] = {0, 1, 2, 4, 24, 26, 35, 38};

  // per-element scratch layout (words; all 16B-aligned)
  float*     E    = scr + sub * ESZ;
  float*     Araw = E;                          // 200 words (overlaid by qhh/h2hh)
  _Float16*  qhh  = (_Float16*)E;               // [5][48] halves  (words 0..119)
  _Float16*  h2hh = (_Float16*)(E + 120);       // [5][32] halves  (words 120..199)
  float*     tb   = E + 200;                    // [9][8] f32 padded rows (200..271)
  _Float16*  sshh = (_Float16*)(E + 272);       // 136 halves (272..339)
  _Float16*  tthh = (_Float16*)(E + 340);       // 48 halves (340..363)
  _Float16*  thh  = (_Float16*)(E + 364);       // [5][16] halves (364..403)
  _Float16*  h0hh = (_Float16*)(E + 404);       // 32 halves (404..419)
  float*     sL   = E + 420;                    // 16 f32 (420..435)

  for (int grp = blockIdx.x; grp < nGroups; grp += gridDim.x) {
    const int b = grp * 16 + sub;

    // ---- phase 0: stage raw t2s (200 f32) + scalars ----
    {
      const float4* src = (const float4*)(t2s + (size_t)b * 200);
      float4* Av = (float4*)Araw;
      Av[lane] = src[lane];
      if (lane < 18) Av[lane + 32] = src[lane + 32];
    }
    float sreg[16];
    {
      const float4* sv = (const float4*)(sc + (size_t)b * 16);
      #pragma unroll
      for (int i4 = 0; i4 < 4; i4++) {
        float4 x = sv[i4];
        sreg[4 * i4 + 0] = x.x; sreg[4 * i4 + 1] = x.y;
        sreg[4 * i4 + 2] = x.z; sreg[4 * i4 + 3] = x.w;
      }
      if (lane < 4) ((float4*)sL)[lane] = sv[lane];
    }

    // ---- phase 1: build t rows (fp32 tb padded + fp16 th transposed) ----
    #pragma unroll
    for (int it = 0; it < 2; it++) {
      int idx = lane + 32 * it;
      if (idx < 40) {
        int r = idx / 5, c = idx % 5;
        float val = Araw[L2R[r] * 5 + c];
        tb[r * 8 + c] = val;
        thh[c * 16 + r] = (_Float16)val;
      }
    }
    { // kernel-sum row: 25 lanes partial + width-32 shfl gather
      int l25 = lane % 25;
      int c2 = l25 / 5, j2 = l25 % 5;
      float acc = 0.f;
      #pragma unroll
      for (int rr = 0; rr < 8; rr++) acc += Araw[(j2 + 5 * rr) * 5 + c2];
      float tot = __shfl(acc, 5 * c2 + 0, 32) + __shfl(acc, 5 * c2 + 1, 32)
                + __shfl(acc, 5 * c2 + 2, 32) + __shfl(acc, 5 * c2 + 3, 32)
                + __shfl(acc, 5 * c2 + 4, 32);
      if (lane < 25 && j2 == 0) { tb[64 + c2] = tot; thh[c2 * 16 + 8] = (_Float16)tot; }
    }
    // ---- zero all fp16 pads (regions overlay poisoned/raw data) ----
    if (lane < 23) {
      if (lane < 15)      qhh[(lane / 3) * 48 + 45 + lane % 3] = (_Float16)0.f;
      else if (lane < 18) tthh[45 + (lane - 15)] = (_Float16)0.f;
      else                thh[(lane - 18) * 16 + 9] = (_Float16)0.f;
    }

    // ---- phase 2: pairs -> tt (fp16) + qT (fp16) ----
    #pragma unroll
    for (int it = 0; it < 2; it++) {
      int idx = lane + 32 * it;
      if (idx < 45) {
        int pr = pairs9[idx];
        int pu = pr & 15, pv = pr >> 4;
        float4 u4 = *(const float4*)(tb + pu * 8); float u5 = tb[pu * 8 + 4];
        float4 v4 = *(const float4*)(tb + pv * 8); float v5 = tb[pv * 8 + 4];
        float tu[5] = {u4.x, u4.y, u4.z, u4.w, u5};
        float tv[5] = {v4.x, v4.y, v4.z, v4.w, v5};
        float tt = tu[0]*tv[0] + tu[1]*tv[1] + tu[2]*tv[2] + tu[3]*tv[3] + tu[4]*tv[4];
        tthh[idx] = (_Float16)tt;
        float qk[5] = {0, 0, 0, 0, 0};
        #pragma unroll
        for (int s = 0; s < 32; s++)
          qk[CKa[s]] = fmaf(C.v[s], tu[CIa[s]] * tv[CJa[s]], qk[CKa[s]]);
        #pragma unroll
        for (int k = 0; k < 5; k++) qhh[k * 48 + idx] = (_Float16)qk[k];
      }
    }

    // ---- phase 3a: ss pair products (fp16) ----
    #pragma unroll
    for (int ii = 0; ii < 3; ii++) {
      int slot = lane + 32 * ii;
      if (slot < 68) {
        int t = sspair[slot];
        int u0 = t & 15, v0 = (t >> 4) & 15, u1 = (t >> 8) & 15, v1 = (t >> 12) & 15;
        *(half2_t*)(sshh + 2 * slot) = pk2(sL[u0] * sL[v0], sL[u1] * sL[v1]);
      }
    }

    // ---- phase 3b: h0[w] = W000.ss + W110.tt (4 independent acc chains) ----
    float h0;
    {
      float hA = 0.f, hB = 0.f, hC = 0.f, hD = 0.f;
      const _Float16* wr = slabh + HW000 + w * 136;
      #pragma unroll
      for (int i = 0; i < 17; i++) {
        H8 a, d;
        a.v = *(const half8_t*)(wr + 8 * i);
        d.v = *(const half8_t*)(sshh + 8 * i);
        hA = dot2f(a.p[0], d.p[0], hA); hB = dot2f(a.p[1], d.p[1], hB);
        hC = dot2f(a.p[2], d.p[2], hC); hD = dot2f(a.p[3], d.p[3], hD);
      }
      const _Float16* wr2 = slabh + HW110 + w * 56;
      #pragma unroll
      for (int i = 0; i < 6; i++) {
        H8 a, d;
        a.v = *(const half8_t*)(wr2 + 8 * i);
        d.v = *(const half8_t*)(tthh + 8 * i);
        hA = dot2f(a.p[0], d.p[0], hA); hB = dot2f(a.p[1], d.p[1], hB);
        hC = dot2f(a.p[2], d.p[2], hC); hD = dot2f(a.p[3], d.p[3], hD);
      }
      h0 = (hA + hB) + (hC + hD);
    }
    h0hh[w] = (_Float16)h0;

    // ---- phase 4: Cvv = WC.s ; h2 = Cvv.t ----
    half2_t sh[8];
    #pragma unroll
    for (int i = 0; i < 8; i++) sh[i] = pk2(sreg[2 * i], sreg[2 * i + 1]);
    float Cvv[9];
    {
      const _Float16* wr = slabh + HWC + w * 152;
      #pragma unroll
      for (int v = 0; v < 9; v++) {
        H8 a0, a1;
        a0.v = *(const half8_t*)(wr + v * 16);
        a1.v = *(const half8_t*)(wr + v * 16 + 8);
        float accA = dot2f(a0.p[0], sh[0], 0.f);
        float accB = dot2f(a0.p[1], sh[1], 0.f);
        accA = dot2f(a0.p[2], sh[2], accA); accB = dot2f(a0.p[3], sh[3], accB);
        accA = dot2f(a1.p[0], sh[4], accA); accB = dot2f(a1.p[1], sh[5], accB);
        accA = dot2f(a1.p[2], sh[6], accA); accB = dot2f(a1.p[3], sh[7], accB);
        Cvv[v] = accA + accB;
      }
    }
    half2_t cpk[5] = { pk2(Cvv[0], Cvv[1]), pk2(Cvv[2], Cvv[3]),
                       pk2(Cvv[4], Cvv[5]), pk2(Cvv[6], Cvv[7]), pk2(Cvv[8], 0.f) };
    float h2r[5];
    #pragma unroll
    for (int k = 0; k < 5; k++) {
      H8 d; d.v = *(const half8_t*)(thh + k * 16);
      half2_t d4 = *(const half2_t*)(thh + k * 16 + 8);
      float acc = dot2f(cpk[0], d.p[0], 0.f);
      acc = dot2f(cpk[1], d.p[1], acc);
      acc = dot2f(cpk[2], d.p[2], acc);
      acc = dot2f(cpk[3], d.p[3], acc);
      acc = dot2f(cpk[4], d4, acc);
      h2r[k] = acc;
    }

    // ---- phase 5: h2 += W111 . qT (2 acc chains per k) ----
    {
      H8 wk[6];
      const _Float16* wr = slabh + HW111 + w * 56;
      #pragma unroll
      for (int i = 0; i < 6; i++) wk[i].v = *(const half8_t*)(wr + 8 * i);
      #pragma unroll
      for (int k = 0; k < 5; k++) {
        const _Float16* qr = qhh + k * 48;
        float accA = h2r[k], accB = 0.f;
        #pragma unroll
        for (int i = 0; i < 6; i++) {
          H8 d; d.v = *(const half8_t*)(qr + 8 * i);
          accA = dot2f(wk[i].p[0], d.p[0], accA); accB = dot2f(wk[i].p[1], d.p[1], accB);
          accA = dot2f(wk[i].p[2], d.p[2], accA); accB = dot2f(wk[i].p[3], d.p[3], accB);
        }
        h2r[k] = accA + accB;
      }
    }

    // ---- phase 6: h2 -> fp16 rows [j][32] ----
    #pragma unroll
    for (int k = 0; k < 5; k++) h2hh[k * 32 + w] = (_Float16)h2r[k];

    // ---- phase 7: a[j] = V110[w,:] . h2[:,j] (2 acc chains) ----
    float a5[5];
    {
      H8 wk[4];
      const _Float16* wr = slabh + HV110 + w * 40;
      #pragma unroll
      for (int i = 0; i < 4; i++) wk[i].v = *(const half8_t*)(wr + 8 * i);
      #pragma unroll
      for (int j = 0; j < 5; j++) {
        const _Float16* hr = h2hh + j * 32;
        float accA = 0.f, accB = 0.f;
        #pragma unroll
        for (int i = 0; i < 4; i++) {
          H8 d; d.v = *(const half8_t*)(hr + 8 * i);
          accA = dot2f(wk[i].p[0], d.p[0], accA); accB = dot2f(wk[i].p[1], d.p[1], accB);
          accA = dot2f(wk[i].p[2], d.p[2], accA); accB = dot2f(wk[i].p[3], d.p[3], accB);
        }
        a5[j] = accA + accB;
      }
    }

    // ---- phase 8: g = Mr[w,:] . h0 (2 acc chains) ----
    float g;
    {
      float gA = 0.f, gB = 0.f;
      const _Float16* wr = slabh + HMR + w * 40;
      #pragma unroll
      for (int i = 0; i < 4; i++) {
        H8 a, d;
        a.v = *(const half8_t*)(wr + 8 * i);
        d.v = *(const half8_t*)(h0hh + 8 * i);
        gA = dot2f(a.p[0], d.p[0], gA); gB = dot2f(a.p[1], d.p[1], gB);
        gA = dot2f(a.p[2], d.p[2], gA); gB = dot2f(a.p[3], d.p[3], gB);
      }
      g = gA + gB;
    }

    // ---- phase 9: yv = C.(h2 (x) a); z = DCONST*yv + g*h2; packed reduce ----
    float yv[5] = {0, 0, 0, 0, 0};
    #pragma unroll
    for (int s = 0; s < 32; s++)
      yv[CKa[s]] = fmaf(C.v[s], h2r[CIa[s]] * a5[CJa[s]], yv[CKa[s]]);

    const float DCONST = sqrtf(5.0f / 3072.0f);
    float z[5];
    #pragma unroll
    for (int k = 0; k < 5; k++) z[k] = fmaf(DCONST, yv[k], g * h2r[k]);

    half2_t z01 = pk2(z[0], z[1]);
    half2_t z23 = pk2(z[2], z[3]);
    float   z4  = z[4];
    #pragma unroll
    for (int st = 1; st <= 16; st <<= 1) {
      z01 = z01 + i2h(__shfl_xor(h2i(z01), st));
      z23 = z23 + i2h(__shfl_xor(h2i(z23), st));
      z4 += __shfl_xor(z4, st);
    }
    if (lane < 5) {
      float val = (lane == 0) ? (float)z01[0]
                : (lane == 1) ? (float)z01[1]
                : (lane == 2) ? (float)z23[0]
                : (lane == 3) ? (float)z23[1] : z4;
      out[(size_t)b * 5 + lane] = val;
    }
  }
}

// ---------------------------------------------------------------------------
extern "C" void kernel_launch(void* const* d_in, const int* in_sizes, int n_in,
                              void* d_out, int out_size, void* d_ws, size_t ws_size,
                              hipStream_t stream) {
  (void)n_in; (void)out_size; (void)d_ws; (void)ws_size;

  CPack C;
  computeC(C);

  ech_setup<<<64, 256, 0, stream>>>(
      (const float*)d_in[2], (const float*)d_in[3], (const float*)d_in[4],
      (const float*)d_in[5], (const float*)d_in[6], (const float*)d_in[7],
      (const float*)d_in[8], (const float*)d_in[9]);

  const int B = in_sizes[0] / 16;
  const int nGroups = B / 16;
  ech_main<<<512, 512, 0, stream>>>(
      (const float*)d_in[0], (const float*)d_in[1], (float*)d_out, nGroups, C);
}

// Round 10
// 261.841 us; speedup vs baseline: 2.6736x; 1.5563x over previous
//
#include <hip/hip_runtime.h>
#include <cmath>

// ---------------------------------------------------------------------------
// EquivariantCorrectionHead — round 10: partial MFMA restructure.
// Converted to per-wave MFMA over the block's 16-element tile:
//   h0   = [W000|W110][32x192] @ sstt[192x16e]   (wave 0, 12 MFMAs)
//   g    = Mr[32x32] @ h0^T[32x16e]              (wave 0 chain, 2 MFMAs)
//   Cvv  = wc[288x32pad] @ spad[32x16e]          (waves 1-2, 9 tiles each)
// Weights pre-packed in A-fragment layout (m=lane&15, k=quad*8+j) by setup;
// element vectors read as B-frags (k=quad*8+j, n=lane&15); D: m=quad*4+reg,
// n=lane&15 (m89/m120-verified layouts). Phases 0-3a, 4b, 5, 6, 7, 9 keep the
// verified R9 dot2 structure. 2 barriers per iteration.
// ---------------------------------------------------------------------------

#define DEVINL static __device__ __forceinline__

typedef _Float16 half2_t __attribute__((ext_vector_type(2)));
typedef _Float16 half8_t __attribute__((ext_vector_type(8)));
typedef float    f32x4_t __attribute__((ext_vector_type(4)));
union H8 { half8_t v; half2_t p[4]; };

// ---- slab offsets in HALVES ----
#define FW0   0        // 12 x 512: A-frags of [W000|W110] (2 Mtiles x 6 Ksteps)
#define FWC   6144     // 18 x 512: A-frags of wc (m=w*9+v, k=u pad32)
#define FMR   15360    // 2 x 512:  A-frags of Mr
#define HW111 16384    // 32 x 56 (45 used, pads 0), dot2 rows
#define HV110 18176    // 32 x 40 (32 used), dot2 rows
#define SLABH 19456

__device__ __align__(16) _Float16 g_wsh[SLABH];

struct CPack { float v[32]; };

// C222 nonzero superset (exact O(3) parity selection rule)
static constexpr int CIa[32] = {2,2,2,4,2,4,4,4, 2,0,0, 2,1,1, 2,3,3, 4,0,0, 4,1,1, 4,3,3, 0,0,1,1,3,3};
static constexpr int CJa[32] = {2,2,4,2,4,2,4,4, 0,2,0, 1,2,1, 3,2,3, 0,4,0, 1,4,1, 3,4,3, 1,3,0,3,0,1};
static constexpr int CKa[32] = {2,4,2,2,4,4,2,4, 0,0,2, 1,1,2, 3,3,2, 0,0,4, 1,1,4, 3,3,4, 3,1,3,0,1,0};

__host__ __device__ inline void tri_uv(int p, int n, int& u, int& v) {
  int base = 0;
  for (int x = 0; x < n; x++) {
    int c = n - x;
    if (p < base + c) { u = x; v = x + (p - base); return; }
    base += c;
  }
  u = n - 1; v = n - 1;
}

// ---- host analytic C222 (round-4 proven sign) ----
static double h_trE3(const double A[3][3], const double B[3][3], const double C[3][3]) {
  double t = 0.0;
  for (int r = 0; r < 3; r++)
    for (int c = 0; c < 3; c++) {
      double ab = 0.0;
      for (int m = 0; m < 3; m++) ab += A[r][m] * B[m][c];
      t += ab * C[c][r];
    }
  return t;
}
static void computeC(CPack& out) {
  const double s2i = 0.7071067811865475244, s6i = 0.4082482904638630164;
  double E[5][3][3] = {
    {{0, s2i, 0}, {s2i, 0, 0}, {0, 0, 0}},
    {{0, 0, 0}, {0, 0, s2i}, {0, s2i, 0}},
    {{-s6i, 0, 0}, {0, -s6i, 0}, {0, 0, 2.0 * s6i}},
    {{0, 0, s2i}, {0, 0, 0}, {s2i, 0, 0}},
    {{s2i, 0, 0}, {0, -s2i, 0}, {0, 0, 0}}
  };
  double T[125], nrm = 0.0;
  for (int f = 0; f < 125; f++) {
    int i = f / 25, j = (f / 5) % 5, k = f % 5;
    T[f] = h_trE3(E[i], E[j], E[k]) + h_trE3(E[i], E[k], E[j]);
    nrm += T[f] * T[f];
  }
  nrm = std::sqrt(nrm);
  int am = 0; double mx = std::fabs(T[0]);
  for (int q = 1; q < 125; q++) { double v = std::fabs(T[q]); if (v > mx) { mx = v; am = q; } }
  const double scale = ((T[am] < 0.0) ? 1.0 : -1.0) / nrm;
  for (int s = 0; s < 32; s++)
    out.v[s] = (float)(scale * T[(CIa[s] * 5 + CJa[s]) * 5 + CKa[s]]);
}

// ---- device helpers ----
DEVINL float dot2f(half2_t a, half2_t b, float c) {
#if __has_builtin(__builtin_amdgcn_fdot2)
  return __builtin_amdgcn_fdot2(a, b, c, false);
#else
  return fmaf((float)a[0], (float)b[0], fmaf((float)a[1], (float)b[1], c));
#endif
}
DEVINL half2_t pk2(float a, float b) {
  auto r = __builtin_amdgcn_cvt_pkrtz(a, b);
  half2_t o;
  __builtin_memcpy(&o, &r, sizeof(o));
  return o;
}
DEVINL int h2i(half2_t h) { int i; __builtin_memcpy(&i, &h, 4); return i; }
DEVINL half2_t i2h(int i) { half2_t h; __builtin_memcpy(&h, &i, 4); return h; }
DEVINL f32x4_t mfma16(half8_t a, half8_t b, f32x4_t c) {
  return __builtin_amdgcn_mfma_f32_16x16x32_f16(a, b, c, 0, 0, 0);
}
DEVINL void store4h(_Float16* p, f32x4_t d) {   // pack 4 f32 -> 4 halves, b64 store
  int2 v;
  v.x = h2i(pk2(d[0], d[1]));
  v.y = h2i(pk2(d[2], d[3]));
  *(int2*)p = v;
}

// ---------------------------------------------------------------------------
// Setup: pack weights (dot2 rows + MFMA A-fragments), constants folded
// ---------------------------------------------------------------------------
__global__ void ech_setup(const float* __restrict__ w000, const float* __restrict__ w110,
                          const float* __restrict__ w011, const float* __restrict__ w101,
                          const float* __restrict__ w111, const float* __restrict__ v010,
                          const float* __restrict__ v100, const float* __restrict__ v110) {
  const float c0   = 1.0f / sqrtf(337.0f);
  const float inv5 = 0.44721359549995794f;
  const float c2   = sqrtf(5.0f / 369.0f);
  const float dm   = sqrtf(5.0f / 3072.0f) * inv5;
  int gid = blockIdx.x * blockDim.x + threadIdx.x;
  int gs  = gridDim.x * blockDim.x;

  // FW0: A-frags of combined W[w][p], p<136: sym-w000(tri16), p<181: sym-w110, else 0
  for (int idx = gid; idx < 6144; idx += gs) {
    int j = idx & 7, L = (idx >> 3) & 63, tk = idx >> 9;   // tk = mt*6+ks
    int mt = tk / 6, ks = tk % 6;
    int w = mt * 16 + (L & 15);
    int p = ks * 32 + (L >> 4) * 8 + j;
    float x = 0.0f;
    if (p < 136) {
      int u, v; tri_uv(p, 16, u, v);
      x = c0 * (w000[(u * 16 + v) * 32 + w] + (u != v ? w000[(v * 16 + u) * 32 + w] : 0.0f));
    } else if (p < 181) {
      int u, v; tri_uv(p - 136, 9, u, v);
      x = c0 * inv5 * (w110[(u * 9 + v) * 32 + w] + (u != v ? w110[(v * 9 + u) * 32 + w] : 0.0f));
    }
    g_wsh[FW0 + idx] = (_Float16)x;
  }
  // FWC: A-frags of wc[m=w*9+v][k=u pad32]
  for (int idx = gid; idx < 9216; idx += gs) {
    int j = idx & 7, L = (idx >> 3) & 63, t = idx >> 9;    // t<18
    int m = t * 16 + (L & 15);
    int w = m / 9, v = m % 9;
    int u = (L >> 4) * 8 + j;
    float x = (u < 16) ? c2 * inv5 * (w011[(u * 9 + v) * 32 + w] + w101[(v * 16 + u) * 32 + w]) : 0.0f;
    g_wsh[FWC + idx] = (_Float16)x;
  }
  // FMR: A-frags of Mr[w][u] = dm*(v010[u,w]+v100[w,u])
  for (int idx = gid; idx < 1024; idx += gs) {
    int j = idx & 7, L = (idx >> 3) & 63, mt = idx >> 9;
    int w = mt * 16 + (L & 15);
    int u = (L >> 4) * 8 + j;
    g_wsh[FMR + idx] = (_Float16)(dm * (v010[u * 32 + w] + v100[w * 32 + u]));
  }
  // HW111 dot2 rows (45 used, pads 0)
  for (int idx = gid; idx < 32 * 56; idx += gs) {
    int w = idx / 56, p = idx % 56; float x = 0.0f;
    if (p < 45) { int u, v; tri_uv(p, 9, u, v);
      x = c2 * (w111[(u * 9 + v) * 32 + w] + (u != v ? w111[(v * 9 + u) * 32 + w] : 0.0f)); }
    g_wsh[HW111 + w * 56 + p] = (_Float16)x;
  }
  // HV110 dot2 rows
  for (int idx = gid; idx < 1024; idx += gs) {
    int u = idx / 32, v = idx % 32;
    g_wsh[HV110 + u * 40 + v] = (_Float16)v110[u * 32 + v];
  }
}

// ---------------------------------------------------------------------------
// Main fused kernel
// ---------------------------------------------------------------------------
#define ESZ 440   // per-element scratch words (halves stride = 880)
__global__ void __launch_bounds__(512)
ech_main(const float* __restrict__ sc, const float* __restrict__ t2s,
         float* __restrict__ out, int nGroups, CPack C) {
  __shared__ __align__(16) _Float16 slabh[SLABH];
  __shared__ __align__(16) float scr[16 * ESZ];
  __shared__ __align__(16) _Float16 cvvH[16 * 296];   // [e][m=w*9+v] (288 used)
  __shared__ __align__(16) _Float16 h0st[16 * 40];    // [e][u] (32 used)
  __shared__ __align__(16) _Float16 gst[16 * 40];     // [e][w] (32 used)
  __shared__ int pairs9[48];
  __shared__ int sspair[68];

  const int tid  = threadIdx.x;
  const int lane = tid & 31;
  const int sub  = tid >> 5;
  const int w    = lane;

  for (int i = tid; i < SLABH / 8; i += 512)
    ((float4*)slabh)[i] = ((const float4*)g_wsh)[i];
  if (tid < 45) { int u, v; tri_uv(tid, 9, u, v); pairs9[tid] = u | (v << 4); }
  if (tid < 68) {
    int u0, v0, u1, v1;
    tri_uv(2 * tid, 16, u0, v0);
    tri_uv(2 * tid + 1, 16, u1, v1);
    sspair[tid] = u0 | (v0 << 4) | (u1 << 8) | (v1 << 12);
  }
  __syncthreads();

  constexpr int L2R[8] = {0, 1, 2, 4, 24, 26, 35, 38};

  // per-element scratch layout (words):
  float*     E    = scr + sub * ESZ;
  float*     Araw = E;                          // 0..199 (overlaid by qhh/h2hh)
  _Float16*  qhh  = (_Float16*)E;               // [5][48] halves (words 0..119)
  _Float16*  h2hh = (_Float16*)(E + 120);       // [5][32] halves (words 120..199)
  float*     tb   = E + 200;                    // [9][8] f32 (200..271)
  _Float16*  sshh = (_Float16*)(E + 272);       // 136 halves (272..339)
  _Float16*  tthh = (_Float16*)(E + 340);       // 56 halves (45 used; 340..367)
  _Float16*  thh  = (_Float16*)(E + 368);       // [5][16] halves (368..407)
  float*     sL   = E + 408;                    // 16 f32 (408..423)
  int*       spad = (int*)(E + 424);            // 32 halves as 16 ints (424..439)

  for (int grp = blockIdx.x; grp < nGroups; grp += gridDim.x) {
    const int b = grp * 16 + sub;

    // ======== S1: per-element marshaling (per half-wave) ========
    {
      const float4* src = (const float4*)(t2s + (size_t)b * 200);
      float4* Av = (float4*)Araw;
      Av[lane] = src[lane];
      if (lane < 18) Av[lane + 32] = src[lane + 32];
    }
    {
      const float4* sv = (const float4*)(sc + (size_t)b * 16);
      if (lane < 4) ((float4*)sL)[lane] = sv[lane];
    }
    // spad: halves [u<16 = s, u>=16 = 0] (B-operand of Cvv GEMM)
    if (lane < 16)
      spad[lane] = (lane < 8) ? h2i(pk2(sL[2 * lane], sL[2 * lane + 1])) : 0;

    // phase 1: t rows (fp32 tb padded + fp16 th transposed)
    #pragma unroll
    for (int it = 0; it < 2; it++) {
      int idx = lane + 32 * it;
      if (idx < 40) {
        int r = idx / 5, c = idx % 5;
        float val = Araw[L2R[r] * 5 + c];
        tb[r * 8 + c] = val;
        thh[c * 16 + r] = (_Float16)val;
      }
    }
    { // kernel-sum row
      int l25 = lane % 25;
      int c2 = l25 / 5, j2 = l25 % 5;
      float acc = 0.f;
      #pragma unroll
      for (int rr = 0; rr < 8; rr++) acc += Araw[(j2 + 5 * rr) * 5 + c2];
      float tot = __shfl(acc, 5 * c2 + 0, 32) + __shfl(acc, 5 * c2 + 1, 32)
                + __shfl(acc, 5 * c2 + 2, 32) + __shfl(acc, 5 * c2 + 3, 32)
                + __shfl(acc, 5 * c2 + 4, 32);
      if (lane < 25 && j2 == 0) { tb[64 + c2] = tot; thh[c2 * 16 + 8] = (_Float16)tot; }
    }
    // pads: q 45..47 per k (15), tthh 45..55 (11), thh [k][9] (5)
    if (lane < 31) {
      if (lane < 15)      qhh[(lane / 3) * 48 + 45 + lane % 3] = (_Float16)0.f;
      else if (lane < 26) tthh[45 + (lane - 15)] = (_Float16)0.f;
      else                thh[(lane - 26) * 16 + 9] = (_Float16)0.f;
    }

    // phase 2: pairs -> tt (fp16) + qT (fp16)
    #pragma unroll
    for (int it = 0; it < 2; it++) {
      int idx = lane + 32 * it;
      if (idx < 45) {
        int pr = pairs9[idx];
        int pu = pr & 15, pv = pr >> 4;
        float4 u4 = *(const float4*)(tb + pu * 8); float u5 = tb[pu * 8 + 4];
        float4 v4 = *(const float4*)(tb + pv * 8); float v5 = tb[pv * 8 + 4];
        float tu[5] = {u4.x, u4.y, u4.z, u4.w, u5};
        float tv[5] = {v4.x, v4.y, v4.z, v4.w, v5};
        float tt = tu[0]*tv[0] + tu[1]*tv[1] + tu[2]*tv[2] + tu[3]*tv[3] + tu[4]*tv[4];
        tthh[idx] = (_Float16)tt;
        float qk[5] = {0, 0, 0, 0, 0};
        #pragma unroll
        for (int s = 0; s < 32; s++)
          qk[CKa[s]] = fmaf(C.v[s], tu[CIa[s]] * tv[CJa[s]], qk[CKa[s]]);
        #pragma unroll
        for (int k = 0; k < 5; k++) qhh[k * 48 + idx] = (_Float16)qk[k];
      }
    }

    // phase 3a: ss pair products (fp16)
    #pragma unroll
    for (int ii = 0; ii < 3; ii++) {
      int slot = lane + 32 * ii;
      if (slot < 68) {
        int t = sspair[slot];
        int u0 = t & 15, v0 = (t >> 4) & 15, u1 = (t >> 8) & 15, v1 = (t >> 12) & 15;
        *(half2_t*)(sshh + 2 * slot) = pk2(sL[u0] * sL[v0], sL[u1] * sL[v1]);
      }
    }
    __syncthreads();   // B1

    // ======== S2: MFMA stage (waves 0-2; others pass through) ========
    {
      const int wid = tid >> 6;
      const int L   = tid & 63;
      const int e2  = L & 15;
      const int q2  = L >> 4;
      const _Float16* scrH = (const _Float16*)scr;
      if (wid == 0) {
        // h0: D[w][e] = Wcomb[32x192] @ sstt[192x16e]
        f32x4_t a0 = {0.f, 0.f, 0.f, 0.f}, a1 = {0.f, 0.f, 0.f, 0.f};
        const _Float16* ssb = scrH + e2 * 880 + 544;   // sstt halves of element e2
        #pragma unroll
        for (int ks = 0; ks < 6; ks++) {
          half8_t bb = *(const half8_t*)(ssb + ks * 32 + q2 * 8);
          half8_t w0 = *(const half8_t*)(slabh + FW0 + ks * 512 + L * 8);
          half8_t w1 = *(const half8_t*)(slabh + FW0 + (6 + ks) * 512 + L * 8);
          a0 = mfma16(w0, bb, a0);
          a1 = mfma16(w1, bb, a1);
        }
        store4h(h0st + e2 * 40 + q2 * 4, a0);
        store4h(h0st + e2 * 40 + 16 + q2 * 4, a1);
        // g: D[w][e] = Mr[32x32] @ h0^T[32x16e]  (same-wave DS ordering)
        half8_t hb = *(const half8_t*)(h0st + e2 * 40 + q2 * 8);
        half8_t m0 = *(const half8_t*)(slabh + FMR + L * 8);
        half8_t m1 = *(const half8_t*)(slabh + FMR + 512 + L * 8);
        f32x4_t z4 = {0.f, 0.f, 0.f, 0.f};
        f32x4_t g0 = mfma16(m0, hb, z4);
        f32x4_t g1 = mfma16(m1, hb, z4);
        store4h(gst + e2 * 40 + q2 * 4, g0);
        store4h(gst + e2 * 40 + 16 + q2 * 4, g1);
      } else if (wid <= 2) {
        // Cvv: D[m=w*9+v][e] = wc[288x32] @ spad[32x16e], 9 tiles per wave
        const _Float16* spb = scrH + e2 * 880 + 848;
        half8_t bb = *(const half8_t*)(spb + q2 * 8);
        const int t0 = (wid - 1) * 9;
        #pragma unroll
        for (int t = 0; t < 9; t++) {
          half8_t wa = *(const half8_t*)(slabh + FWC + (t0 + t) * 512 + L * 8);
          f32x4_t z4 = {0.f, 0.f, 0.f, 0.f};
          f32x4_t d = mfma16(wa, bb, z4);
          store4h(cvvH + e2 * 296 + (t0 + t) * 16 + q2 * 4, d);
        }
      }
    }
    __syncthreads();   // B2

    // ======== S3: per-element finish (per half-wave) ========
    // 4b: h2pre = Cvv . t
    float Cvv[9];
    #pragma unroll
    for (int v = 0; v < 9; v++) Cvv[v] = (float)cvvH[sub * 296 + w * 9 + v];
    half2_t cpk[5] = { pk2(Cvv[0], Cvv[1]), pk2(Cvv[2], Cvv[3]),
                       pk2(Cvv[4], Cvv[5]), pk2(Cvv[6], Cvv[7]), pk2(Cvv[8], 0.f) };
    float h2r[5];
    #pragma unroll
    for (int k = 0; k < 5; k++) {
      H8 d; d.v = *(const half8_t*)(thh + k * 16);
      half2_t d4 = *(const half2_t*)(thh + k * 16 + 8);
      float acc = dot2f(cpk[0], d.p[0], 0.f);
      acc = dot2f(cpk[1], d.p[1], acc);
      acc = dot2f(cpk[2], d.p[2], acc);
      acc = dot2f(cpk[3], d.p[3], acc);
      acc = dot2f(cpk[4], d4, acc);
      h2r[k] = acc;
    }

    // phase 5: h2 += W111 . qT (2 acc chains per k)
    {
      H8 wk[6];
      const _Float16* wr = slabh + HW111 + w * 56;
      #pragma unroll
      for (int i = 0; i < 6; i++) wk[i].v = *(const half8_t*)(wr + 8 * i);
      #pragma unroll
      for (int k = 0; k < 5; k++) {
        const _Float16* qr = qhh + k * 48;
        float accA = h2r[k], accB = 0.f;
        #pragma unroll
        for (int i = 0; i < 6; i++) {
          H8 d; d.v = *(const half8_t*)(qr + 8 * i);
          accA = dot2f(wk[i].p[0], d.p[0], accA); accB = dot2f(wk[i].p[1], d.p[1], accB);
          accA = dot2f(wk[i].p[2], d.p[2], accA); accB = dot2f(wk[i].p[3], d.p[3], accB);
        }
        h2r[k] = accA + accB;
      }
    }

    // phase 6: h2 -> fp16 rows [j][32]
    #pragma unroll
    for (int k = 0; k < 5; k++) h2hh[k * 32 + w] = (_Float16)h2r[k];

    // phase 7: a[j] = V110[w,:] . h2[:,j] (2 acc chains)
    float a5[5];
    {
      H8 wk[4];
      const _Float16* wr = slabh + HV110 + w * 40;
      #pragma unroll
      for (int i = 0; i < 4; i++) wk[i].v = *(const half8_t*)(wr + 8 * i);
      #pragma unroll
      for (int j = 0; j < 5; j++) {
        const _Float16* hr = h2hh + j * 32;
        float accA = 0.f, accB = 0.f;
        #pragma unroll
        for (int i = 0; i < 4; i++) {
          H8 d; d.v = *(const half8_t*)(hr + 8 * i);
          accA = dot2f(wk[i].p[0], d.p[0], accA); accB = dot2f(wk[i].p[1], d.p[1], accB);
          accA = dot2f(wk[i].p[2], d.p[2], accA); accB = dot2f(wk[i].p[3], d.p[3], accB);
        }
        a5[j] = accA + accB;
      }
    }

    // phase 8 result: g from MFMA stage
    float g = (float)gst[sub * 40 + w];

    // phase 9: yv = C.(h2 (x) a); z = DCONST*yv + g*h2; packed reduce
    float yv[5] = {0, 0, 0, 0, 0};
    #pragma unroll
    for (int s = 0; s < 32; s++)
      yv[CKa[s]] = fmaf(C.v[s], h2r[CIa[s]] * a5[CJa[s]], yv[CKa[s]]);

    const float DCONST = sqrtf(5.0f / 3072.0f);
    float z[5];
    #pragma unroll
    for (int k = 0; k < 5; k++) z[k] = fmaf(DCONST, yv[k], g * h2r[k]);

    half2_t z01 = pk2(z[0], z[1]);
    half2_t z23 = pk2(z[2], z[3]);
    float   z4r = z[4];
    #pragma unroll
    for (int st = 1; st <= 16; st <<= 1) {
      z01 = z01 + i2h(__shfl_xor(h2i(z01), st));
      z23 = z23 + i2h(__shfl_xor(h2i(z23), st));
      z4r += __shfl_xor(z4r, st);
    }
    if (lane < 5) {
      float val = (lane == 0) ? (float)z01[0]
                : (lane == 1) ? (float)z01[1]
                : (lane == 2) ? (float)z23[0]
                : (lane == 3) ? (float)z23[1] : z4r;
      out[(size_t)b * 5 + lane] = val;
    }
  }
}

// ---------------------------------------------------------------------------
extern "C" void kernel_launch(void* const* d_in, const int* in_sizes, int n_in,
                              void* d_out, int out_size, void* d_ws, size_t ws_size,
                              hipStream_t stream) {
  (void)n_in; (void)out_size; (void)d_ws; (void)ws_size;

  CPack C;
  computeC(C);

  ech_setup<<<64, 256, 0, stream>>>(
      (const float*)d_in[2], (const float*)d_in[3], (const float*)d_in[4],
      (const float*)d_in[5], (const float*)d_in[6], (const float*)d_in[7],
      (const float*)d_in[8], (const float*)d_in[9]);

  const int B = in_sizes[0] / 16;
  const int nGroups = B / 16;
  ech_main<<<512, 512, 0, stream>>>(
      (const float*)d_in[0], (const float*)d_in[1], (float*)d_out, nGroups, C);
}

// Round 11
// 251.400 us; speedup vs baseline: 2.7847x; 1.0415x over previous
//
#include <hip/hip_runtime.h>
#include <cmath>

// ---------------------------------------------------------------------------
// EquivariantCorrectionHead — round 11: MFMA phases 5 & 7 too.
// 5-stage, 4-barrier pipeline per iteration:
//  S1  marshal (staging, t build, qT->qB per-element, ss) [per half-wave]
//  S2  MFMA: h0+g (w0), Cvv (w1-2), p5 = W111@qT per k (w3-7)
//  S3a h2 = Cvv.t (dot2) + p5; write h2B [per half-wave]
//  S2b MFMA: aB_j = V110 @ h2_j (w0-4)
//  S3c a,g read; final CG + reduce + store [per half-wave]
// Loop-top B1 is the cross-iteration fence for all block-level buffers.
// aB overlays p5 (dead after S3a); qB overlays raw staging (dead after S1).
// LDS ~81KB -> 2 blocks/CU (critical budget).
// ---------------------------------------------------------------------------

#define DEVINL static __device__ __forceinline__

typedef _Float16 half2_t __attribute__((ext_vector_type(2)));
typedef _Float16 half8_t __attribute__((ext_vector_type(8)));
typedef float    f32x4_t __attribute__((ext_vector_type(4)));
union H8 { half8_t v; half2_t p[4]; };

// ---- slab offsets in HALVES ----
#define FW0   0        // 12 x 512: A-frags [W000|W110] (2 Mt x 6 Ks, K=192)
#define FWC   6144     // 18 x 256: A-frags wc (quads 0-1 only; K=16, pad in-reg)
#define FMR   10752    // 2 x 512:  A-frags Mr
#define FW111 11776    // 4 x 512:  A-frags W111 (2 Mt x 2 Ks, K=64, p>=45 zero)
#define FV110 13824    // 2 x 512:  A-frags V110 (2 Mt, K=32)
#define SLABH 14848

__device__ __align__(16) _Float16 g_wsh[SLABH];

struct CPack { float v[32]; };

// C222 nonzero superset (exact O(3) parity selection rule)
static constexpr int CIa[32] = {2,2,2,4,2,4,4,4, 2,0,0, 2,1,1, 2,3,3, 4,0,0, 4,1,1, 4,3,3, 0,0,1,1,3,3};
static constexpr int CJa[32] = {2,2,4,2,4,2,4,4, 0,2,0, 1,2,1, 3,2,3, 0,4,0, 1,4,1, 3,4,3, 1,3,0,3,0,1};
static constexpr int CKa[32] = {2,4,2,2,4,4,2,4, 0,0,2, 1,1,2, 3,3,2, 0,0,4, 1,1,4, 3,3,4, 3,1,3,0,1,0};

__host__ __device__ inline void tri_uv(int p, int n, int& u, int& v) {
  int base = 0;
  for (int x = 0; x < n; x++) {
    int c = n - x;
    if (p < base + c) { u = x; v = x + (p - base); return; }
    base += c;
  }
  u = n - 1; v = n - 1;
}

// ---- host analytic C222 (round-4 proven sign) ----
static double h_trE3(const double A[3][3], const double B[3][3], const double C[3][3]) {
  double t = 0.0;
  for (int r = 0; r < 3; r++)
    for (int c = 0; c < 3; c++) {
      double ab = 0.0;
      for (int m = 0; m < 3; m++) ab += A[r][m] * B[m][c];
      t += ab * C[c][r];
    }
  return t;
}
static void computeC(CPack& out) {
  const double s2i = 0.7071067811865475244, s6i = 0.4082482904638630164;
  double E[5][3][3] = {
    {{0, s2i, 0}, {s2i, 0, 0}, {0, 0, 0}},
    {{0, 0, 0}, {0, 0, s2i}, {0, s2i, 0}},
    {{-s6i, 0, 0}, {0, -s6i, 0}, {0, 0, 2.0 * s6i}},
    {{0, 0, s2i}, {0, 0, 0}, {s2i, 0, 0}},
    {{s2i, 0, 0}, {0, -s2i, 0}, {0, 0, 0}}
  };
  double T[125], nrm = 0.0;
  for (int f = 0; f < 125; f++) {
    int i = f / 25, j = (f / 5) % 5, k = f % 5;
    T[f] = h_trE3(E[i], E[j], E[k]) + h_trE3(E[i], E[k], E[j]);
    nrm += T[f] * T[f];
  }
  nrm = std::sqrt(nrm);
  int am = 0; double mx = std::fabs(T[0]);
  for (int q = 1; q < 125; q++) { double v = std::fabs(T[q]); if (v > mx) { mx = v; am = q; } }
  const double scale = ((T[am] < 0.0) ? 1.0 : -1.0) / nrm;
  for (int s = 0; s < 32; s++)
    out.v[s] = (float)(scale * T[(CIa[s] * 5 + CJa[s]) * 5 + CKa[s]]);
}

// ---- device helpers ----
DEVINL float dot2f(half2_t a, half2_t b, float c) {
#if __has_builtin(__builtin_amdgcn_fdot2)
  return __builtin_amdgcn_fdot2(a, b, c, false);
#else
  return fmaf((float)a[0], (float)b[0], fmaf((float)a[1], (float)b[1], c));
#endif
}
DEVINL half2_t pk2(float a, float b) {
  auto r = __builtin_amdgcn_cvt_pkrtz(a, b);
  half2_t o;
  __builtin_memcpy(&o, &r, sizeof(o));
  return o;
}
DEVINL int h2i(half2_t h) { int i; __builtin_memcpy(&i, &h, 4); return i; }
DEVINL half2_t i2h(int i) { half2_t h; __builtin_memcpy(&h, &i, 4); return h; }
DEVINL f32x4_t mfma16(half8_t a, half8_t b, f32x4_t c) {
  return __builtin_amdgcn_mfma_f32_16x16x32_f16(a, b, c, 0, 0, 0);
}
DEVINL void store4h(_Float16* p, f32x4_t d) {
  int2 v;
  v.x = h2i(pk2(d[0], d[1]));
  v.y = h2i(pk2(d[2], d[3]));
  *(int2*)p = v;
}

// ---------------------------------------------------------------------------
// Setup: pack all weights as MFMA A-fragments (constants folded)
// ---------------------------------------------------------------------------
__global__ void ech_setup(const float* __restrict__ w000, const float* __restrict__ w110,
                          const float* __restrict__ w011, const float* __restrict__ w101,
                          const float* __restrict__ w111, const float* __restrict__ v010,
                          const float* __restrict__ v100, const float* __restrict__ v110) {
  const float c0   = 1.0f / sqrtf(337.0f);
  const float inv5 = 0.44721359549995794f;
  const float c2   = sqrtf(5.0f / 369.0f);
  const float dm   = sqrtf(5.0f / 3072.0f) * inv5;
  int gid = blockIdx.x * blockDim.x + threadIdx.x;
  int gs  = gridDim.x * blockDim.x;

  // FW0: A-frags of combined W[w][p]: p<136 sym-w000(tri16), p<181 sym-w110
  for (int idx = gid; idx < 6144; idx += gs) {
    int j = idx & 7, L = (idx >> 3) & 63, tk = idx >> 9;
    int mt = tk / 6, ks = tk % 6;
    int w = mt * 16 + (L & 15);
    int p = ks * 32 + (L >> 4) * 8 + j;
    float x = 0.0f;
    if (p < 136) {
      int u, v; tri_uv(p, 16, u, v);
      x = c0 * (w000[(u * 16 + v) * 32 + w] + (u != v ? w000[(v * 16 + u) * 32 + w] : 0.0f));
    } else if (p < 181) {
      int u, v; tri_uv(p - 136, 9, u, v);
      x = c0 * inv5 * (w110[(u * 9 + v) * 32 + w] + (u != v ? w110[(v * 9 + u) * 32 + w] : 0.0f));
    }
    g_wsh[FW0 + idx] = (_Float16)x;
  }
  // FWC: A-frags of wc[m=w*9+v][k=u], quads 0-1 only (K=16)
  for (int idx = gid; idx < 4608; idx += gs) {
    int j = idx & 7, L = (idx >> 3) & 31, t = idx >> 8;
    int m = t * 16 + (L & 15);
    int w = m / 9, v = m % 9;
    int u = (L >> 4) * 8 + j;
    g_wsh[FWC + idx] =
        (_Float16)(c2 * inv5 * (w011[(u * 9 + v) * 32 + w] + w101[(v * 16 + u) * 32 + w]));
  }
  // FMR: A-frags of Mr[w][u]
  for (int idx = gid; idx < 1024; idx += gs) {
    int j = idx & 7, L = (idx >> 3) & 63, mt = idx >> 9;
    int w = mt * 16 + (L & 15);
    int u = (L >> 4) * 8 + j;
    g_wsh[FMR + idx] = (_Float16)(dm * (v010[u * 32 + w] + v100[w * 32 + u]));
  }
  // FW111: A-frags (2 Mt x 2 Ks), A[m=w][k=p], p>=45 zero
  for (int idx = gid; idx < 2048; idx += gs) {
    int j = idx & 7, L = (idx >> 3) & 63, t = idx >> 9;
    int mt = t >> 1, ks = t & 1;
    int w = mt * 16 + (L & 15);
    int p = ks * 32 + (L >> 4) * 8 + j;
    float x = 0.0f;
    if (p < 45) { int u, v; tri_uv(p, 9, u, v);
      x = c2 * (w111[(u * 9 + v) * 32 + w] + (u != v ? w111[(v * 9 + u) * 32 + w] : 0.0f)); }
    g_wsh[FW111 + idx] = (_Float16)x;
  }
  // FV110: A-frags (2 Mt), A[m=u][k=v]
  for (int idx = gid; idx < 1024; idx += gs) {
    int j = idx & 7, L = (idx >> 3) & 63, mt = idx >> 9;
    int u = mt * 16 + (L & 15);
    int v = (L >> 4) * 8 + j;
    g_wsh[FV110 + idx] = (_Float16)v110[u * 32 + v];
  }
}

// ---------------------------------------------------------------------------
// Main fused kernel
// ---------------------------------------------------------------------------
#define ESZ 444          // per-element scratch words (half-stride 888)
#define P5MT 272         // p5/aB mt-stride (halves)
#define P5K  544         // p5/aB k-stride
__global__ void __launch_bounds__(512)
ech_main(const float* __restrict__ sc, const float* __restrict__ t2s,
         float* __restrict__ out, int nGroups, CPack C) {
  __shared__ __align__(16) _Float16 slabh[SLABH];       // 29696 B
  __shared__ __align__(16) float scr[16 * ESZ];         // 28416 B
  __shared__ __align__(16) _Float16 unionH[5280];       // p5/aB(2720) + h2B(2560)
  __shared__ __align__(16) _Float16 cvvH[16 * 288];     // 9216 B
  __shared__ __align__(16) _Float16 h0st[16 * 40];      // 1280 B
  __shared__ __align__(16) _Float16 gst[16 * 40];       // 1280 B
  __shared__ int pairs9[48];
  __shared__ int sspair[68];

  const int tid  = threadIdx.x;
  const int lane = tid & 31;
  const int sub  = tid >> 5;
  const int w    = lane;

  _Float16* p5H  = unionH;           // [k][mt][e][16] (aB overlays, same strides)
  _Float16* h2Bb = unionH + 2720;    // [j][e][32]

  for (int i = tid; i < SLABH / 8; i += 512)
    ((float4*)slabh)[i] = ((const float4*)g_wsh)[i];
  if (tid < 45) { int u, v; tri_uv(tid, 9, u, v); pairs9[tid] = u | (v << 4); }
  if (tid < 68) {
    int u0, v0, u1, v1;
    tri_uv(2 * tid, 16, u0, v0);
    tri_uv(2 * tid + 1, 16, u1, v1);
    sspair[tid] = u0 | (v0 << 4) | (u1 << 8) | (v1 << 12);
  }

  constexpr int L2R[8] = {0, 1, 2, 4, 24, 26, 35, 38};

  // per-element scratch (words):
  float*     E    = scr + sub * ESZ;
  float*     Araw = E;                          // 0..199 (qBe overlays 0..159)
  _Float16*  qBe  = (_Float16*)E;               // [k<5][64] halves
  float*     tb   = E + 200;                    // [9][8] f32
  _Float16*  sshh = (_Float16*)(E + 272);       // 136 h  (sstt contiguous ->)
  _Float16*  tthh = (_Float16*)(E + 340);       // 56 h   (45 used + 11 pad)
  _Float16*  thh  = (_Float16*)(E + 368);       // [5][16] h
  float*     sL   = E + 408;                    // 16 f32
  int*       spad = (int*)(E + 424);            // 16 ints (32 halves)

  // one-time pad zeroing (regions never clobbered by staging)
  if (lane < 11)      tthh[45 + lane] = (_Float16)0.f;
  else if (lane < 16) thh[(lane - 11) * 16 + 9] = (_Float16)0.f;
  if (lane >= 24)     spad[lane - 16] = 0;
  __syncthreads();

  for (int grp = blockIdx.x; grp < nGroups; grp += gridDim.x) {
    const int b = grp * 16 + sub;

    // ======== S1: per-element marshaling ========
    {
      const float4* src = (const float4*)(t2s + (size_t)b * 200);
      float4* Av = (float4*)Araw;
      Av[lane] = src[lane];
      if (lane < 18) Av[lane + 32] = src[lane + 32];
      const float4* sv = (const float4*)(sc + (size_t)b * 16);
      if (lane < 4) ((float4*)sL)[lane] = sv[lane];
    }
    if (lane < 8) spad[lane] = h2i(pk2(sL[2 * lane], sL[2 * lane + 1]));

    // phase 1: t rows
    #pragma unroll
    for (int it = 0; it < 2; it++) {
      int idx = lane + 32 * it;
      if (idx < 40) {
        int r = idx / 5, c = idx % 5;
        float val = Araw[L2R[r] * 5 + c];
        tb[r * 8 + c] = val;
        thh[c * 16 + r] = (_Float16)val;
      }
    }
    { // kernel-sum row
      int l25 = lane % 25;
      int c2 = l25 / 5, j2 = l25 % 5;
      float acc = 0.f;
      #pragma unroll
      for (int rr = 0; rr < 8; rr++) acc += Araw[(j2 + 5 * rr) * 5 + c2];
      float tot = __shfl(acc, 5 * c2 + 0, 32) + __shfl(acc, 5 * c2 + 1, 32)
                + __shfl(acc, 5 * c2 + 2, 32) + __shfl(acc, 5 * c2 + 3, 32)
                + __shfl(acc, 5 * c2 + 4, 32);
      if (lane < 25 && j2 == 0) { tb[64 + c2] = tot; thh[c2 * 16 + 8] = (_Float16)tot; }
    }

    // phase 2: pairs -> tt + qB (overlays Araw; pads re-zeroed here)
    #pragma unroll
    for (int it = 0; it < 2; it++) {
      int idx = lane + 32 * it;
      if (idx < 45) {
        int pr = pairs9[idx];
        int pu = pr & 15, pv = pr >> 4;
        float4 u4 = *(const float4*)(tb + pu * 8); float u5 = tb[pu * 8 + 4];
        float4 v4 = *(const float4*)(tb + pv * 8); float v5 = tb[pv * 8 + 4];
        float tu[5] = {u4.x, u4.y, u4.z, u4.w, u5};
        float tv[5] = {v4.x, v4.y, v4.z, v4.w, v5};
        float tt = tu[0]*tv[0] + tu[1]*tv[1] + tu[2]*tv[2] + tu[3]*tv[3] + tu[4]*tv[4];
        tthh[idx] = (_Float16)tt;
        float qk[5] = {0, 0, 0, 0, 0};
        #pragma unroll
        for (int s = 0; s < 32; s++)
          qk[CKa[s]] = fmaf(C.v[s], tu[CIa[s]] * tv[CJa[s]], qk[CKa[s]]);
        #pragma unroll
        for (int k = 0; k < 5; k++) qBe[k * 64 + idx] = (_Float16)qk[k];
      } else {
        #pragma unroll
        for (int k = 0; k < 5; k++) qBe[k * 64 + idx] = (_Float16)0.f;
      }
    }

    // phase 3a: ss pair products
    #pragma unroll
    for (int ii = 0; ii < 3; ii++) {
      int slot = lane + 32 * ii;
      if (slot < 68) {
        int t = sspair[slot];
        int u0 = t & 15, v0 = (t >> 4) & 15, u1 = (t >> 8) & 15, v1 = (t >> 12) & 15;
        *(half2_t*)(sshh + 2 * slot) = pk2(sL[u0] * sL[v0], sL[u1] * sL[v1]);
      }
    }
    __syncthreads();   // B1 (also cross-iteration fence)

    // ======== S2: MFMA stage 1 ========
    {
      const int wid = tid >> 6;
      const int L   = tid & 63;
      const int e2  = L & 15;
      const int q2  = L >> 4;
      const _Float16* scrH = (const _Float16*)scr;
      if (wid == 0) {
        // h0 + g
        f32x4_t a0 = {0.f, 0.f, 0.f, 0.f}, a1 = {0.f, 0.f, 0.f, 0.f};
        const _Float16* ssb = scrH + e2 * (2 * ESZ) + 544;
        #pragma unroll
        for (int ks = 0; ks < 6; ks++) {
          half8_t bb = *(const half8_t*)(ssb + ks * 32 + q2 * 8);
          a0 = mfma16(*(const half8_t*)(slabh + FW0 + ks * 512 + L * 8), bb, a0);
          a1 = mfma16(*(const half8_t*)(slabh + FW0 + (6 + ks) * 512 + L * 8), bb, a1);
        }
        store4h(h0st + e2 * 40 + q2 * 4, a0);
        store4h(h0st + e2 * 40 + 16 + q2 * 4, a1);
        half8_t hb = *(const half8_t*)(h0st + e2 * 40 + q2 * 8);
        f32x4_t z4 = {0.f, 0.f, 0.f, 0.f};
        f32x4_t g0 = mfma16(*(const half8_t*)(slabh + FMR + L * 8), hb, z4);
        f32x4_t g1 = mfma16(*(const half8_t*)(slabh + FMR + 512 + L * 8), hb, z4);
        store4h(gst + e2 * 40 + q2 * 4, g0);
        store4h(gst + e2 * 40 + 16 + q2 * 4, g1);
      } else if (wid <= 2) {
        // Cvv
        const _Float16* spb = scrH + e2 * (2 * ESZ) + 848;
        half8_t bb = *(const half8_t*)(spb + q2 * 8);
        const int t0 = (wid - 1) * 9;
        half8_t wz = {0, 0, 0, 0, 0, 0, 0, 0};
        #pragma unroll
        for (int t = 0; t < 9; t++) {
          half8_t wa = (q2 < 2) ? *(const half8_t*)(slabh + FWC + (t0 + t) * 256 + L * 8) : wz;
          f32x4_t z4 = {0.f, 0.f, 0.f, 0.f};
          f32x4_t d = mfma16(wa, bb, z4);
          store4h(cvvH + e2 * 288 + (t0 + t) * 16 + q2 * 4, d);
        }
      } else {
        // p5_k = W111 @ qT_k  (k = wid-3)
        const int k = wid - 3;
        const _Float16* qb = scrH + e2 * (2 * ESZ) + k * 64;
        f32x4_t d0 = {0.f, 0.f, 0.f, 0.f}, d1 = {0.f, 0.f, 0.f, 0.f};
        #pragma unroll
        for (int ks = 0; ks < 2; ks++) {
          half8_t bb = *(const half8_t*)(qb + ks * 32 + q2 * 8);
          d0 = mfma16(*(const half8_t*)(slabh + FW111 + ks * 512 + L * 8), bb, d0);
          d1 = mfma16(*(const half8_t*)(slabh + FW111 + (2 + ks) * 512 + L * 8), bb, d1);
        }
        store4h(p5H + k * P5K + e2 * 16 + q2 * 4, d0);
        store4h(p5H + k * P5K + P5MT + e2 * 16 + q2 * 4, d1);
      }
    }
    __syncthreads();   // B2

    // ======== S3a: h2 = Cvv.t + p5; write h2B ========
    float Cvv[9];
    #pragma unroll
    for (int v = 0; v < 9; v++) Cvv[v] = (float)cvvH[sub * 288 + w * 9 + v];
    half2_t cpk[5] = { pk2(Cvv[0], Cvv[1]), pk2(Cvv[2], Cvv[3]),
                       pk2(Cvv[4], Cvv[5]), pk2(Cvv[6], Cvv[7]), pk2(Cvv[8], 0.f) };
    float h2r[5];
    #pragma unroll
    for (int k = 0; k < 5; k++) {
      H8 d; d.v = *(const half8_t*)(thh + k * 16);
      half2_t d4 = *(const half2_t*)(thh + k * 16 + 8);
      float acc = dot2f(cpk[0], d.p[0], 0.f);
      acc = dot2f(cpk[1], d.p[1], acc);
      acc = dot2f(cpk[2], d.p[2], acc);
      acc = dot2f(cpk[3], d.p[3], acc);
      acc = dot2f(cpk[4], d4, acc);
      h2r[k] = acc + (float)p5H[k * P5K + (w >> 4) * P5MT + sub * 16 + (w & 15)];
    }
    #pragma unroll
    for (int k = 0; k < 5; k++) h2Bb[k * 512 + sub * 32 + w] = (_Float16)h2r[k];
    __syncthreads();   // B3

    // ======== S2b: aB_j = V110 @ h2_j (waves 0-4) ========
    {
      const int wid = tid >> 6;
      const int L   = tid & 63;
      const int e2  = L & 15;
      const int q2  = L >> 4;
      if (wid < 5) {
        const int j = wid;
        half8_t bb = *(const half8_t*)(h2Bb + j * 512 + e2 * 32 + q2 * 8);
        f32x4_t z4 = {0.f, 0.f, 0.f, 0.f};
        f32x4_t d0 = mfma16(*(const half8_t*)(slabh + FV110 + L * 8), bb, z4);
        f32x4_t d1 = mfma16(*(const half8_t*)(slabh + FV110 + 512 + L * 8), bb, z4);
        store4h(p5H + j * P5K + e2 * 16 + q2 * 4, d0);          // aB overlays p5
        store4h(p5H + j * P5K + P5MT + e2 * 16 + q2 * 4, d1);
      }
    }
    __syncthreads();   // B4

    // ======== S3c: final ========
    float a5[5];
    #pragma unroll
    for (int j = 0; j < 5; j++)
      a5[j] = (float)p5H[j * P5K + (w >> 4) * P5MT + sub * 16 + (w & 15)];
    float g = (float)gst[sub * 40 + w];

    float yv[5] = {0, 0, 0, 0, 0};
    #pragma unroll
    for (int s = 0; s < 32; s++)
      yv[CKa[s]] = fmaf(C.v[s], h2r[CIa[s]] * a5[CJa[s]], yv[CKa[s]]);

    const float DCONST = sqrtf(5.0f / 3072.0f);
    float z[5];
    #pragma unroll
    for (int k = 0; k < 5; k++) z[k] = fmaf(DCONST, yv[k], g * h2r[k]);

    half2_t z01 = pk2(z[0], z[1]);
    half2_t z23 = pk2(z[2], z[3]);
    float   z4r = z[4];
    #pragma unroll
    for (int st = 1; st <= 16; st <<= 1) {
      z01 = z01 + i2h(__shfl_xor(h2i(z01), st));
      z23 = z23 + i2h(__shfl_xor(h2i(z23), st));
      z4r += __shfl_xor(z4r, st);
    }
    if (lane < 5) {
      float val = (lane == 0) ? (float)z01[0]
                : (lane == 1) ? (float)z01[1]
                : (lane == 2) ? (float)z23[0]
                : (lane == 3) ? (float)z23[1] : z4r;
      out[(size_t)b * 5 + lane] = val;
    }
  }
}

// ---------------------------------------------------------------------------
extern "C" void kernel_launch(void* const* d_in, const int* in_sizes, int n_in,
                              void* d_out, int out_size, void* d_ws, size_t ws_size,
                              hipStream_t stream) {
  (void)n_in; (void)out_size; (void)d_ws; (void)ws_size;

  CPack C;
  computeC(C);

  ech_setup<<<64, 256, 0, stream>>>(
      (const float*)d_in[2], (const float*)d_in[3], (const float*)d_in[4],
      (const float*)d_in[5], (const float*)d_in[6], (const float*)d_in[7],
      (const float*)d_in[8], (const float*)d_in[9]);

  const int B = in_sizes[0] / 16;
  const int nGroups = B / 16;
  ech_main<<<512, 512, 0, stream>>>(
      (const float*)d_in[0], (const float*)d_in[1], (float*)d_out, nGroups, C);
}